// Round 1
// baseline (537.455 us; speedup 1.0000x reference)
//
#include <hip/hip_runtime.h>

// PowerSpectrum: values[S,N,L,M,Q] -> out[S,N,L*Q*Q]
// out[s,n,l,q,p] = (1/sqrt(2l+1)) * sum_{m<2l+1} v[s,n,l,m,q] * v[s,n,l,m,p]
// S=4, N=2000, L=4, M=7, Q=64. Write-BW bound (524 MB out vs 57 MB in).

#define PS_S 4
#define PS_N 2000
#define PS_L 4
#define PS_M 7
#define PS_Q 64

__global__ __launch_bounds__(256) void PowerSpectrum_kernel(
    const float* __restrict__ values, float* __restrict__ out) {
    // one block per (s, n, l); bid = ((s*N + n)*L + l)
    const int bid = blockIdx.x;
    const int l = bid & (PS_L - 1);          // L == 4 (power of 2)
    const float* __restrict__ vin = values + (size_t)bid * (PS_M * PS_Q);
    float* __restrict__ o = out + (size_t)bid * (PS_Q * PS_Q);

    __shared__ float v[PS_M][PS_Q];          // 7*64*4 = 1792 B

    const int t = threadIdx.x;
    // stage V tile: 448 floats = 112 float4, fully coalesced
    if (t < (PS_M * PS_Q) / 4) {
        ((float4*)&v[0][0])[t] = ((const float4*)vin)[t];
    }
    __syncthreads();

    const int meff = 2 * l + 1;              // wave-uniform (same l for whole block)
    const float cg = rsqrtf((float)meff);

    const int p = (t & 15) * 4;              // column base (float4)
    const int q0 = t >> 4;                   // row within 16-row band

    #pragma unroll
    for (int r = 0; r < 4; ++r) {
        const int q = r * 16 + q0;
        float4 acc = make_float4(0.f, 0.f, 0.f, 0.f);
        for (int m = 0; m < meff; ++m) {
            const float a = v[m][q];         // 16-lane broadcast, conflict-free
            const float4 b = *(const float4*)&v[m][p];
            acc.x += a * b.x;
            acc.y += a * b.y;
            acc.z += a * b.z;
            acc.w += a * b.w;
        }
        acc.x *= cg; acc.y *= cg; acc.z *= cg; acc.w *= cg;
        // flat offset within this (s,n,l) tile: q*Q + p = r*1024 + t*4
        // -> consecutive lanes store consecutive float4s (perfect coalescing)
        *(float4*)&o[q * PS_Q + p] = acc;
    }
}

extern "C" void kernel_launch(void* const* d_in, const int* in_sizes, int n_in,
                              void* d_out, int out_size, void* d_ws, size_t ws_size,
                              hipStream_t stream) {
    const float* values = (const float*)d_in[0];
    float* out = (float*)d_out;
    const int n_blocks = PS_S * PS_N * PS_L;   // 32000
    PowerSpectrum_kernel<<<n_blocks, 256, 0, stream>>>(values, out);
}